// Round 10
// baseline (248.506 us; speedup 1.0000x reference)
//
#include <hip/hip_runtime.h>
#include <math.h>

// Problem constants: N=500000, NFEAT=64, K=8, HK=64
constexpr int NS    = 500000;
constexpr int NF    = 64;
constexpr int KG    = 8;
constexpr int HKC   = 64;
constexpr int NCELL = KG * HKC;            // 512 histogram cells
constexpr int SLICE = HKC * NF;            // 4096 halves = 8 KB per (g, hi|lo)
constexpr int RPT   = 16;                  // rows per tile (one wave-tile)
constexpr int NTILE = NS / RPT;            // 31250 (exact)
constexpr int TPB   = 1024;                // 16 waves per block
constexpr int BPH   = (NTILE + 15) / 16;   // 1954 blocks per group-half
constexpr int NBLK  = 2 * BPH;             // 3908

typedef __attribute__((ext_vector_type(8))) _Float16 half8;
typedef __attribute__((ext_vector_type(4))) float f32x4;

// xor-16 within 32-lane halves: ds_swizzle BitMode offset 0x401F
__device__ __forceinline__ float swz16_f(float v) {
    return __int_as_float(__builtin_amdgcn_ds_swizzle(__float_as_int(v), 0x401F));
}
__device__ __forceinline__ int swz16_i(int v) {
    return __builtin_amdgcn_ds_swizzle(v, 0x401F);
}

// order-preserving float -> u32 key (monotone increasing, finite inputs)
__device__ __forceinline__ unsigned fkey(float v) {
    const unsigned b = __float_as_uint(v);
    return (b & 0x80000000u) ? ~b : (b | 0x80000000u);
}

// Kernel 1: w = exp(z) split to fp16 hi/lo; zero A; minkey = all-ones.
__global__ void prep_kernel(const float* __restrict__ z,
                            _Float16* __restrict__ w_hi,
                            _Float16* __restrict__ w_lo,
                            float* __restrict__ A,
                            unsigned long long* __restrict__ minkey) {
    const int i = blockIdx.x * blockDim.x + threadIdx.x;   // 512x256 = 131072
    if (i < KG * HKC * NF) {
        float w = expf(z[i]);
        _Float16 h = (_Float16)w;           // RNE
        w_hi[i] = h;
        w_lo[i] = (_Float16)(w - (float)h); // residual: ~2^-22 total pair error
    }
    if (i < NCELL) A[i] = 0.0f;
    for (int j = i; j < NS; j += 512 * 256)
        minkey[j] = 0xFFFFFFFFFFFFFFFFull;
}

// Main kernel R16: group-split for 32 waves/CU.
// R15 post-mortem falsified the shared-issue model (cutting matrix+VALU
// cycles left time flat) -> latency-bound at 16 waves/CU; occupancy was
// pinned by 131KB LDS (1 block/CU) x ~90-reg waves (4/SIMD). R16 splits
// the 8 groups across block PAIRS: 65KB LDS/block -> 2 blocks/CU, and
// __launch_bounds__(1024,8) with RPW=16 state (X 16 + W 8 + acc 16 +
// temps ~= 56 regs) -> 8 waves/SIMD, 32 waves/CU: double the TLP that
// the stall profile said was missing. Compute (MFMA order hh,lh,hl;
// s0,s1; fmax tree; descending h-scan; swz16+bperm32 combine) is
// bit-identical to R9. Cross-half min folds via one order-preserving-key
// atomicMin(u64) per row (min v, tie -> smaller code = smaller absolute
// g — exactly R9's strict-< semantics). LDS/block: 65536 + 1024 B.
__global__ __launch_bounds__(TPB, 8) void monn_mfma_kernel(
    const float* __restrict__ x,
    const _Float16* __restrict__ w_hi,
    const _Float16* __restrict__ w_lo,
    const float* __restrict__ t,
    unsigned long long* __restrict__ minkey) {

    __shared__ __align__(16) char smem[2 * 4 * 8192];   // 4g hi @0, lo @32768
    __shared__ __align__(16) float t_lds[4 * HKC];      // 1 KB (this half)

    const int tid   = threadIdx.x;
    const int half  = blockIdx.x & 1;
    const int gbase = half * 4;

    // --- stage this half's W (64 KB, coalesced, XOR-swizzled) + t ---
    {
        const float4* sh = reinterpret_cast<const float4*>(w_hi + (size_t)gbase * SLICE);
        const float4* sl = reinterpret_cast<const float4*>(w_lo + (size_t)gbase * SLICE);
#pragma unroll
        for (int i = 0; i < 2; ++i) {
            const int ci  = i * 1024 + tid;         // 16B chunk id, 0..2047
            const int row = (ci >> 3) & 63;         // w-col within group
            const int ch  = ci & 7;                 // 16B chunk within row
            const int addr = (ci >> 9) * 8192 + row * 128 + ((ch ^ (row & 7)) << 4);
            *reinterpret_cast<float4*>(smem + addr)         = sh[ci];
            *reinterpret_cast<float4*>(smem + 32768 + addr) = sl[ci];
        }
        if (tid < 64)
            reinterpret_cast<float4*>(t_lds)[tid] =
                reinterpret_cast<const float4*>(t + gbase * HKC)[tid];
    }
    __syncthreads();   // no further barriers: early exit below is safe

    const int tile = (blockIdx.x >> 1) * 16 + (tid >> 6);
    if (tile >= NTILE) return;   // 14 tail waves per half

    const int lane = tid & 63;
    const int m  = lane & 15;
    const int q  = lane >> 4;
    const int q4 = q * 4;
    const int a32 = ((lane ^ 32) << 2);   // ds_bpermute byte-addr for xor-32
    const int x7  = m & 7;
    const int rb0 = m * 128 + (((0 + q) ^ x7) << 4);
    const int rb1 = m * 128 + (((4 + q) ^ x7) << 4);

    const long base = (long)tile * RPT;

    // --- Load 16 x rows, split to fp16 hi/lo (B-operand layout) ---
    half8 Xh[2], Xl[2];
    {
        const float* xp = x + (base + m) * NF;
#pragma unroll
        for (int s = 0; s < 2; ++s) {
            const int k0 = s * 32 + q * 8;
            const float4 v0 = *reinterpret_cast<const float4*>(xp + k0);
            const float4 v1 = *reinterpret_cast<const float4*>(xp + k0 + 4);
            const float f[8] = {v0.x, v0.y, v0.z, v0.w, v1.x, v1.y, v1.z, v1.w};
#pragma unroll
            for (int j = 0; j < 8; ++j) {
                _Float16 h = (_Float16)f[j];
                Xh[s][j] = h;
                Xl[s][j] = (_Float16)(f[j] - (float)h);
            }
        }
    }

    float bestv = INFINITY;
    int   bestc = 0;

#pragma unroll 1
    for (int g = 0; g < 4; ++g) {
        // acc init: bias folded; lane's w-cols are c*16 + q4 + j
        f32x4 acc[4];
#pragma unroll
        for (int c = 0; c < 4; ++c) {
            const float4 tv = *reinterpret_cast<const float4*>(
                t_lds + g * HKC + c * 16 + q4);
            acc[c] = (f32x4){tv.x, tv.y, tv.z, tv.w};
        }

        // MFMA: per-acc order hh, lh, hl within each s, s0 then s1 —
        // identical to R9 per accumulator -> bit-identical output.
        // W read pairwise (8 VGPR live) to stay under the 64-reg cap.
#pragma unroll
        for (int s = 0; s < 2; ++s) {
            const int rb = (s ? rb1 : rb0) + g * 8192;
#pragma unroll
            for (int c = 0; c < 4; ++c) {
                const half8 Wh = *reinterpret_cast<const half8*>(smem + rb + c * 2048);
                const half8 Wl = *reinterpret_cast<const half8*>(smem + 32768 + rb + c * 2048);
                acc[c] = __builtin_amdgcn_mfma_f32_16x16x32_f16(Wh, Xh[s], acc[c], 0, 0, 0);
                acc[c] = __builtin_amdgcn_mfma_f32_16x16x32_f16(Wl, Xh[s], acc[c], 0, 0, 0);
                acc[c] = __builtin_amdgcn_mfma_f32_16x16x32_f16(Wh, Xl[s], acc[c], 0, 0, 0);
            }
        }

        // --- epilogue: exact R9 form (rt dimension = 1) ---
        float t01 = fmaxf(acc[0][0], acc[0][1]);
        float t23 = fmaxf(acc[0][2], acc[0][3]);
        float t45 = fmaxf(acc[1][0], acc[1][1]);
        float t67 = fmaxf(acc[1][2], acc[1][3]);
        float t89 = fmaxf(acc[2][0], acc[2][1]);
        float tab = fmaxf(acc[2][2], acc[2][3]);
        float tcd = fmaxf(acc[3][0], acc[3][1]);
        float tef = fmaxf(acc[3][2], acc[3][3]);
        float v = fmaxf(fmaxf(fmaxf(t01, t23), fmaxf(t45, t67)),
                        fmaxf(fmaxf(t89, tab), fmaxf(tcd, tef)));
        // equality scan, descending w-col: last write = smallest ->
        // jnp.argmax first-occurrence semantics (w-col = c*16 + q4 + j)
        int h = 0;
#pragma unroll
        for (int c = 3; c >= 0; --c)
#pragma unroll
            for (int j = 3; j >= 0; --j)
                h = (acc[c][j] == v) ? (c * 16 + j) : h;
        h |= q4;
        // cross-q combine (4 lanes, stride 16): xor16 + xor32
        {
            float v2 = swz16_f(v);
            int   h2 = swz16_i(h);
            bool take = (v2 > v) || (v2 == v && h2 < h);
            v = take ? v2 : v;  h = take ? h2 : h;
            float v3 = __int_as_float(__builtin_amdgcn_ds_bpermute(a32, __float_as_int(v)));
            int   h3 = __builtin_amdgcn_ds_bpermute(a32, h);
            take = (v3 > v) || (v3 == v && h3 < h);
            v = take ? v3 : v;  h = take ? h3 : h;
        }
        // running min over this half's groups: strict < keeps first
        const bool better = v < bestv;
        bestv = fminf(bestv, v);
        bestc = better ? (((gbase + g) << 6) | h) : bestc;
    }

    // fold across halves: key = fkey(v) || code. min -> min v; tie ->
    // smaller code = smaller absolute g (matches sequential strict-<).
    if (q == 0) {
        const unsigned long long key =
            ((unsigned long long)fkey(bestv) << 32) | (unsigned)bestc;
        atomicMin(&minkey[base + m], key);
    }
}

// Kernel 3: decode y from the winning key; histogram codes into A.
__global__ void final_kernel(const unsigned long long* __restrict__ minkey,
                             float* __restrict__ y,
                             float* __restrict__ A) {
    __shared__ unsigned lhist[NCELL];
    const int tid = threadIdx.x;
    for (int i = tid; i < NCELL; i += 256) lhist[i] = 0u;
    __syncthreads();
    for (int i = blockIdx.x * 256 + tid; i < NS; i += gridDim.x * 256) {
        const unsigned long long key = minkey[i];
        const unsigned k = (unsigned)(key >> 32);
        const unsigned b = (k & 0x80000000u) ? (k ^ 0x80000000u) : ~k;
        y[i] = __uint_as_float(b);
        atomicAdd(&lhist[(unsigned)key & (NCELL - 1)], 1u);
    }
    __syncthreads();
    for (int i = tid; i < NCELL; i += 256) {
        const unsigned c = lhist[i];
        if (c) atomicAdd(&A[i], (float)c);
    }
}

extern "C" void kernel_launch(void* const* d_in, const int* in_sizes, int n_in,
                              void* d_out, int out_size, void* d_ws, size_t ws_size,
                              hipStream_t stream) {
    const float* x = (const float*)d_in[0];  // [NS, NF]
    const float* z = (const float*)d_in[1];  // [KG, HKC, NF]
    const float* t = (const float*)d_in[2];  // [KG, HKC]

    float* y = (float*)d_out;        // [NS]
    float* A = (float*)d_out + NS;   // [NCELL]

    _Float16* w_hi = (_Float16*)d_ws;                          // 64 KB
    _Float16* w_lo = w_hi + (size_t)KG * HKC * NF;             // 64 KB
    unsigned long long* minkey =
        (unsigned long long*)((char*)d_ws + 2 * sizeof(_Float16) * KG * HKC * NF);
    // need = 131072 + 500000*8 = 4.13 MB — same known-fit budget as the
    // R7 partial buffer.

    prep_kernel<<<512, 256, 0, stream>>>(z, w_hi, w_lo, A, minkey);
    monn_mfma_kernel<<<NBLK, TPB, 0, stream>>>(x, w_hi, w_lo, t, minkey);
    final_kernel<<<512, 256, 0, stream>>>(minkey, y, A);
}